// Round 1
// 215.429 us; speedup vs baseline: 1.0234x; 1.0234x over previous
//
#include <hip/hip_runtime.h>
#include <hip/hip_bf16.h>
#include <stdint.h>

typedef unsigned short u16;
typedef __attribute__((ext_vector_type(8))) short short8;
typedef __attribute__((ext_vector_type(4))) float f32x4;

#define BATCH 4096
// output region offsets (f32 elements) in d_out: out, h_mix, out_k, h_k
#define OFF_OUT  0
#define OFF_HMIX (BATCH * 256)
#define OFF_OK   (OFF_HMIX + BATCH * 512)
#define OFF_HK   (OFF_OK + BATCH * 256 * 8)

// ws layout (u16/bf16 elements): xb, hb, Wihb, Whhb, Woutb, Tb, Ob (~67 MB)
#define WS_XB   0
#define WS_HB   (2097152)
#define WS_WIH  (4194304)
#define WS_WHH  (6291456)
#define WS_WOUT (8388608)
#define WS_T    (8519680)    // 4096x4096 bf16 plane
#define WS_OB   (25296896)   // 4096x2048 bf16 plane

__device__ __forceinline__ float b2f(u16 v) {
  union { uint32_t u; float f; } c; c.u = ((uint32_t)v) << 16; return c.f;
}
__device__ __forceinline__ u16 f2b(float f) {
  union { float f; uint32_t u; } c; c.f = f;
  uint32_t u = c.u;
  return (u16)((u + 0x7fffu + ((u >> 16) & 1u)) >> 16);  // RNE
}

// async global->LDS, 16B per lane. LDS dest = wave-uniform base + lane*16.
__device__ __forceinline__ void gload16(const u16* g, u16* l) {
  __builtin_amdgcn_global_load_lds(
      (const __attribute__((address_space(1))) void*)g,
      (__attribute__((address_space(3))) void*)l, 16, 0, 0);
}

// ---------------------------------------------------------------------------
// K0: f32 -> bf16 conversion of x, h, W_ih, W_hh, W_out into ws.
// ---------------------------------------------------------------------------
__global__ __launch_bounds__(256) void k0_cvt(
    const float* __restrict__ x, const float* __restrict__ h,
    const float* __restrict__ Wih, const float* __restrict__ Whh,
    const float* __restrict__ Wout, u16* __restrict__ ws) {
  const int i = blockIdx.x * 256 + threadIdx.x;
  const float* src; int j; size_t dst;
  if      (i <  524288) { src = x;    j = i;           dst = WS_XB;   }
  else if (i < 1048576) { src = h;    j = i -  524288; dst = WS_HB;   }
  else if (i < 1572864) { src = Wih;  j = i - 1048576; dst = WS_WIH;  }
  else if (i < 2097152) { src = Whh;  j = i - 1572864; dst = WS_WHH;  }
  else                  { src = Wout; j = i - 2097152; dst = WS_WOUT; }
  const float4 v = ((const float4*)src)[j];
  ushort4 o;
  o.x = f2b(v.x); o.y = f2b(v.y); o.z = f2b(v.z); o.w = f2b(v.w);
  ((ushort4*)(ws + dst))[j] = o;
}

// ---------------------------------------------------------------------------
// K1: Tb[b][k*512+n] = tanh( x[b]·W_ih[k][n] + h[b]·W_hh[k][n] )  (bf16 plane)
// 4096x4096x1024 bf16 GEMM, tanh epilogue.
// 256x256 tile, BK=64, 8 waves (2Mx4N, 128x64 per wave), 8-phase schedule:
//   per K-tile 4 phases {ds_read frags | stage 1 half-tile | barrier |
//   lgkmcnt(0) | setprio(1) 16xMFMA setprio(0) | barrier}, double-buffered
//   128 KiB LDS, counted s_waitcnt vmcnt(2) ONCE per K-tile (never 0 in
//   steady state) so staging loads stay in flight across barriers.
// Region overwrite schedule (one phase after last read of the -2 tile):
//   P1: stage A-hi(t+1)  P2: B-lo(t+1)  P3: B-hi(t+1)  P4: A-lo(t+2)
// B fragments held in registers across all 4 phases (reads: 12,4,8,0).
// LDS chunk-XOR swizzle identical to the verified 128² kernel.
// ---------------------------------------------------------------------------
__global__ __launch_bounds__(512, 2) void k1_gemm_tanh(
    const u16* __restrict__ xb, const u16* __restrict__ hb,
    const u16* __restrict__ Wih, const u16* __restrict__ Whh,
    u16* __restrict__ Tb) {
  __shared__ u16 S[65536];   // [buf0: A 256x64 | B 256x64][buf1: A | B] = 128 KiB
  const int tid  = threadIdx.x;          // 0..511
  const int lane = tid & 63;
  const int w    = tid >> 6;             // 0..7
  const int wm   = w >> 2;               // 0..1  (M half)
  const int wn   = w & 3;                // 0..3  (N quarter)
  const int quad = lane >> 4, rl = lane & 15, l7 = lane & 7;
  const int sr   = tid >> 3;             // 0..63 staging row-in-pass
  const int sc   = ((tid & 7) ^ (sr & 7)) * 8;   // swizzled source chunk

  // XCD-chunked bijective swizzle: 256 wg = 8 XCD x 32; each XCD gets 2 B-panels
  const int wg  = blockIdx.x;
  const int lin = ((wg & 7) << 5) | (wg >> 3);
  const int bx  = lin & 15;
  const int by  = lin >> 4;
  const int row0 = bx * 256;
  const int col0 = by * 256;             // j = k*512 + n; 256 | 512 -> single-k tile
  const int kk   = col0 >> 9;
  const int nh0  = col0 & 511;

  const u16* const As2[2] = { xb, hb };
  const u16* const Bs2[2] = { Wih + (size_t)kk * 262144, Whh + (size_t)kk * 262144 };

  // region: 0=A-lo 1=A-hi 2=B-lo 3=B-hi (half = 128 rows); 2 x gload16/thread
  auto stage = [&](int tile, int region) {
    if (tile >= 16) return;
    const int g    = tile >> 3;          // 0: x/Wih, 1: h/Whh
    const int ko   = (tile & 7) * 64;
    const int isB  = region >> 1;
    const int half = region & 1;
    const u16* src = isB ? Bs2[g] : As2[g];
    const int r0   = (isB ? nh0 : row0) + half * 128;
    u16* dst = S + (tile & 1) * 32768 + isB * 16384 + half * 8192;
    const u16* s0 = src + (size_t)(r0 + sr) * 512 + ko + sc;
    gload16(s0,            dst + tid * 8);
    gload16(s0 + 64 * 512, dst + 4096 + tid * 8);
  };

  auto ldA = [&](int buf, int mi, int ks) -> short8 {
    return *(const short8*)&S[buf * 32768 +
                              (wm * 128 + mi * 16 + rl) * 64 +
                              ((ks * 4 + quad) ^ l7) * 8];
  };
  auto ldB = [&](int buf, int j, int ks) -> short8 {
    return *(const short8*)&S[buf * 32768 + 16384 +
                              (wn * 64 + j * 16 + rl) * 64 +
                              ((ks * 4 + quad) ^ l7) * 8];
  };

  f32x4 acc[8][4] = {};
  short8 af[4][2], bf[4][2];

  // prologue: tile0 fully + A-lo(1); allow A-lo(1) in flight
  stage(0, 0); stage(0, 1); stage(0, 2); stage(0, 3); stage(1, 0);
  asm volatile("s_waitcnt vmcnt(2)" ::: "memory");
  __builtin_amdgcn_s_barrier();

#pragma unroll 1
  for (int t = 0; t < 16; ++t) {
    const int buf = t & 1;

    // ---- P1: Q0 = m0-3 x n0-1  (12 ds_reads)
#pragma unroll
    for (int m = 0; m < 4; ++m) { af[m][0] = ldA(buf, m, 0); af[m][1] = ldA(buf, m, 1); }
#pragma unroll
    for (int j = 0; j < 2; ++j) { bf[j][0] = ldB(buf, j, 0); bf[j][1] = ldB(buf, j, 1); }
    stage(t + 1, 1);
    __builtin_amdgcn_s_barrier();
    asm volatile("s_waitcnt lgkmcnt(0)" ::: "memory");
    __builtin_amdgcn_s_setprio(1);
#pragma unroll
    for (int m = 0; m < 4; ++m)
#pragma unroll
      for (int n = 0; n < 2; ++n)
#pragma unroll
        for (int ks = 0; ks < 2; ++ks)
          acc[m][n] = __builtin_amdgcn_mfma_f32_16x16x32_bf16(af[m][ks], bf[n][ks], acc[m][n], 0, 0, 0);
    __builtin_amdgcn_s_setprio(0);
    __builtin_amdgcn_s_barrier();

    // ---- P2: Q1 = m0-3 x n2-3  (4 ds_reads; af reused)
#pragma unroll
    for (int j = 2; j < 4; ++j) { bf[j][0] = ldB(buf, j, 0); bf[j][1] = ldB(buf, j, 1); }
    stage(t + 1, 2);
    __builtin_amdgcn_s_barrier();
    asm volatile("s_waitcnt lgkmcnt(0)" ::: "memory");
    __builtin_amdgcn_s_setprio(1);
#pragma unroll
    for (int m = 0; m < 4; ++m)
#pragma unroll
      for (int n = 2; n < 4; ++n)
#pragma unroll
        for (int ks = 0; ks < 2; ++ks)
          acc[m][n] = __builtin_amdgcn_mfma_f32_16x16x32_bf16(af[m][ks], bf[n][ks], acc[m][n], 0, 0, 0);
    __builtin_amdgcn_s_setprio(0);
    __builtin_amdgcn_s_barrier();

    // ---- P3: Q2 = m4-7 x n2-3  (8 ds_reads; bf reused)
#pragma unroll
    for (int m = 0; m < 4; ++m) { af[m][0] = ldA(buf, 4 + m, 0); af[m][1] = ldA(buf, 4 + m, 1); }
    stage(t + 1, 3);
    __builtin_amdgcn_s_barrier();
    asm volatile("s_waitcnt lgkmcnt(0)" ::: "memory");
    __builtin_amdgcn_s_setprio(1);
#pragma unroll
    for (int m = 0; m < 4; ++m)
#pragma unroll
      for (int n = 2; n < 4; ++n)
#pragma unroll
        for (int ks = 0; ks < 2; ++ks)
          acc[4 + m][n] = __builtin_amdgcn_mfma_f32_16x16x32_bf16(af[m][ks], bf[n][ks], acc[4 + m][n], 0, 0, 0);
    __builtin_amdgcn_s_setprio(0);
    __builtin_amdgcn_s_barrier();

    // ---- P4: Q3 = m4-7 x n0-1  (0 ds_reads) + boundary vmcnt
    stage(t + 2, 0);
    __builtin_amdgcn_s_barrier();
    __builtin_amdgcn_s_setprio(1);
#pragma unroll
    for (int m = 0; m < 4; ++m)
#pragma unroll
      for (int n = 0; n < 2; ++n)
#pragma unroll
        for (int ks = 0; ks < 2; ++ks)
          acc[4 + m][n] = __builtin_amdgcn_mfma_f32_16x16x32_bf16(af[m][ks], bf[n][ks], acc[4 + m][n], 0, 0, 0);
    __builtin_amdgcn_s_setprio(0);
    // allow only A-lo(t+2)'s 2 loads in flight; drain when it wasn't issued
    if (t < 14) asm volatile("s_waitcnt vmcnt(2)" ::: "memory");
    else        asm volatile("s_waitcnt vmcnt(0)" ::: "memory");
    __builtin_amdgcn_s_barrier();
  }

  // epilogue: tanh -> bf16 -> LDS transpose (stride 264 u16, 16B rows, 2 halves)
#pragma unroll 1
  for (int hp = 0; hp < 2; ++hp) {
    if (wm == hp) {
#pragma unroll
      for (int m = 0; m < 8; ++m)
#pragma unroll
        for (int n = 0; n < 4; ++n)
#pragma unroll
          for (int r = 0; r < 4; ++r) {
            const int lr = m * 16 + quad * 4 + r;       // row within half
            const float v = acc[m][n][r];
            const float e = __expf(2.0f * v);           // tanh, saturating, no NaN
            S[lr * 264 + wn * 64 + n * 16 + rl] = f2b(1.0f - 2.0f / (e + 1.0f));
          }
    }
    asm volatile("s_waitcnt lgkmcnt(0)" ::: "memory");  // drain ds_writes pre-barrier
    __builtin_amdgcn_s_barrier();
#pragma unroll
    for (int p = 0; p < 8; ++p) {
      const int idx = p * 512 + tid;    // 0..4095
      const int c = idx & 31, rr = idx >> 5;
      *(short8*)&Tb[(size_t)(row0 + hp * 128 + rr) * 4096 + col0 + c * 8] =
          *(const short8*)&S[rr * 264 + c * 8];
    }
    __builtin_amdgcn_s_barrier();
  }
}

// ---------------------------------------------------------------------------
// K2: Ob[b][k*256+y] = sum_n Tb[b][k*512+n] * Wout[y][n]   (8 batched GEMMs)
// bf16 in / bf16 out (plane in ws). Same structure + transpose epilogue.
// ---------------------------------------------------------------------------
__global__ __launch_bounds__(256) void k2_gemm_out(
    const u16* __restrict__ Tb, const u16* __restrict__ Wout,
    u16* __restrict__ Ob) {
  __shared__ u16 S[128 * 136];
  u16* As = S;
  u16* Bs = S + 128 * 64;
  const int tid  = threadIdx.x;
  const int lane = tid & 63;
  const int w    = tid >> 6;
  const int wm   = w >> 1, wn = w & 1;
  const int row0 = blockIdx.x * 128;
  const int y0   = blockIdx.y * 128;
  const int kk   = blockIdx.z;
  const int sr   = tid >> 3;
  const int sc   = ((tid & 7) ^ ((tid >> 3) & 7)) * 8;
  const int ldsw = (w * 8) * 64;

  f32x4 acc[4][4] = {};

  for (int kt = 0; kt < 8; ++kt) {
    const int kb = kt * 64;
#pragma unroll
    for (int ro = 0; ro < 4; ++ro) {
      gload16(Tb + (size_t)(row0 + ro * 32 + sr) * 4096 + kk * 512 + kb + sc,
              &As[ro * 32 * 64 + ldsw]);
      gload16(Wout + (size_t)(y0 + ro * 32 + sr) * 512 + kb + sc,
              &Bs[ro * 32 * 64 + ldsw]);
    }
    __syncthreads();
    const int l7 = lane & 7, quad = lane >> 4, rl = lane & 15;
#pragma unroll
    for (int ks = 0; ks < 2; ++ks) {
      short8 af[4], bf[4];
      const int cs = ((ks * 4 + quad) ^ l7) * 8;
#pragma unroll
      for (int i = 0; i < 4; ++i)
        af[i] = *(const short8*)&As[(wm * 64 + i * 16 + rl) * 64 + cs];
#pragma unroll
      for (int j = 0; j < 4; ++j)
        bf[j] = *(const short8*)&Bs[(wn * 64 + j * 16 + rl) * 64 + cs];
#pragma unroll
      for (int i = 0; i < 4; ++i)
#pragma unroll
        for (int j = 0; j < 4; ++j)
          acc[i][j] = __builtin_amdgcn_mfma_f32_16x16x32_bf16(af[i], bf[j], acc[i][j], 0, 0, 0);
    }
    __syncthreads();
  }

  const int quad = lane >> 4, cl = lane & 15;
#pragma unroll
  for (int i = 0; i < 4; ++i)
#pragma unroll
    for (int j = 0; j < 4; ++j)
#pragma unroll
      for (int r = 0; r < 4; ++r) {
        const int row = wm * 64 + i * 16 + quad * 4 + r;
        const int col = wn * 64 + j * 16 + cl;
        S[row * 136 + col] = f2b(acc[i][j][r]);
      }
  __syncthreads();
#pragma unroll
  for (int it = 0; it < 8; ++it) {
    const int idx = it * 256 + tid;
    const int c = idx & 15;
    const int r = idx >> 4;
    *(short8*)&Ob[(size_t)(row0 + r) * 2048 + kk * 256 + y0 + c * 8] =
        *(const short8*)&S[r * 136 + c * 8];
  }
}

// ---------------------------------------------------------------------------
// K3: epilogue. Block b: reads Tb row + Ob row (bf16, ws), writes f32
// interleaved h_k / out_k (coalesced float4) + h_mix + out.
// ---------------------------------------------------------------------------
__global__ __launch_bounds__(512) void k3_epi(const float* __restrict__ pi,
                                              const u16* __restrict__ Tb,
                                              const u16* __restrict__ Ob,
                                              float* __restrict__ dout) {
  const int b   = blockIdx.x;
  const int tid = threadIdx.x;

  float pif[8];
#pragma unroll
  for (int k = 0; k < 8; ++k) pif[k] = pi[b * 8 + k];

  float tv[8]; float hm = 0.0f;
#pragma unroll
  for (int k = 0; k < 8; ++k) {
    const float v = b2f(Tb[(size_t)b * 4096 + k * 512 + tid]);
    tv[k] = v; hm += pif[k] * v;
  }
  float4* tw = (float4*)&dout[OFF_HK + (size_t)b * 4096 + tid * 8];
  tw[0] = make_float4(tv[0], tv[1], tv[2], tv[3]);
  tw[1] = make_float4(tv[4], tv[5], tv[6], tv[7]);
  dout[OFF_HMIX + (size_t)b * 512 + tid] = hm;

  if (tid < 256) {
    float ov[8]; float om = 0.0f;
#pragma unroll
    for (int k = 0; k < 8; ++k) {
      const float v = b2f(Ob[(size_t)b * 2048 + k * 256 + tid]);
      ov[k] = v; om += pif[k] * v;
    }
    float4* ow = (float4*)&dout[OFF_OK + (size_t)b * 2048 + tid * 8];
    ow[0] = make_float4(ov[0], ov[1], ov[2], ov[3]);
    ow[1] = make_float4(ov[4], ov[5], ov[6], ov[7]);
    dout[OFF_OUT + (size_t)b * 256 + tid] = om;
  }
}

extern "C" void kernel_launch(void* const* d_in, const int* in_sizes, int n_in,
                              void* d_out, int out_size, void* d_ws, size_t ws_size,
                              hipStream_t stream) {
  const float* x    = (const float*)d_in[0];
  const float* h    = (const float*)d_in[1];
  const float* pi   = (const float*)d_in[2];
  const float* Wih  = (const float*)d_in[3];
  const float* Whh  = (const float*)d_in[4];
  const float* Wout = (const float*)d_in[5];
  float* out = (float*)d_out;
  u16* ws  = (u16*)d_ws;

  k0_cvt<<<dim3(8320), 256, 0, stream>>>(x, h, Wih, Whh, Wout, ws);
  k1_gemm_tanh<<<dim3(256), 512, 0, stream>>>(
      ws + WS_XB, ws + WS_HB, ws + WS_WIH, ws + WS_WHH, ws + WS_T);
  k2_gemm_out<<<dim3(32, 2, 8), 256, 0, stream>>>(ws + WS_T, ws + WS_WOUT, ws + WS_OB);
  k3_epi<<<dim3(BATCH), 512, 0, stream>>>(pi, ws + WS_T, ws + WS_OB, out);
}

// Round 3
// 214.589 us; speedup vs baseline: 1.0274x; 1.0039x over previous
//
#include <hip/hip_runtime.h>
#include <hip/hip_bf16.h>
#include <stdint.h>

typedef unsigned short u16;
typedef __attribute__((ext_vector_type(8))) short short8;
typedef __attribute__((ext_vector_type(4))) float f32x4;

#define BATCH 4096
// output region offsets (f32 elements) in d_out: out, h_mix, out_k, h_k
#define OFF_OUT  0
#define OFF_HMIX (BATCH * 256)
#define OFF_OK   (OFF_HMIX + BATCH * 512)
#define OFF_HK   (OFF_OK + BATCH * 256 * 8)

// ws layout (u16/bf16 elements): xb, hb, Wihb, Whhb, Woutb, Tb, Ob (~67 MB)
#define WS_XB   0
#define WS_HB   (2097152)
#define WS_WIH  (4194304)
#define WS_WHH  (6291456)
#define WS_WOUT (8388608)
#define WS_T    (8519680)    // 4096x4096 bf16 plane
#define WS_OB   (25296896)   // 4096x2048 bf16 plane

__device__ __forceinline__ float b2f(u16 v) {
  union { uint32_t u; float f; } c; c.u = ((uint32_t)v) << 16; return c.f;
}
__device__ __forceinline__ u16 f2b(float f) {
  union { float f; uint32_t u; } c; c.f = f;
  uint32_t u = c.u;
  return (u16)((u + 0x7fffu + ((u >> 16) & 1u)) >> 16);  // RNE
}

// async global->LDS, 16B per lane. LDS dest = wave-uniform base + lane*16.
__device__ __forceinline__ void gload16(const u16* g, u16* l) {
  __builtin_amdgcn_global_load_lds(
      (const __attribute__((address_space(1))) void*)g,
      (__attribute__((address_space(3))) void*)l, 16, 0, 0);
}

// ---------------------------------------------------------------------------
// K0: f32 -> bf16 conversion of x, h, W_ih, W_hh, W_out into ws.
// ---------------------------------------------------------------------------
__global__ __launch_bounds__(256) void k0_cvt(
    const float* __restrict__ x, const float* __restrict__ h,
    const float* __restrict__ Wih, const float* __restrict__ Whh,
    const float* __restrict__ Wout, u16* __restrict__ ws) {
  const int i = blockIdx.x * 256 + threadIdx.x;
  const float* src; int j; size_t dst;
  if      (i <  524288) { src = x;    j = i;           dst = WS_XB;   }
  else if (i < 1048576) { src = h;    j = i -  524288; dst = WS_HB;   }
  else if (i < 1572864) { src = Wih;  j = i - 1048576; dst = WS_WIH;  }
  else if (i < 2097152) { src = Whh;  j = i - 1572864; dst = WS_WHH;  }
  else                  { src = Wout; j = i - 2097152; dst = WS_WOUT; }
  const float4 v = ((const float4*)src)[j];
  ushort4 o;
  o.x = f2b(v.x); o.y = f2b(v.y); o.z = f2b(v.z); o.w = f2b(v.w);
  ((ushort4*)(ws + dst))[j] = o;
}

// ---------------------------------------------------------------------------
// K1: Tb[b][k*512+n] = tanh( x[b]·W_ih[k][n] + h[b]·W_hh[k][n] )  (bf16 plane)
// 4096x4096x1024 bf16 GEMM, tanh epilogue.
// 256x256 tile, BK=64, 8 waves (2Mx4N, 128x64 per wave), 4 phases/K-tile,
// double-buffered 128 KiB LDS.
//
// Deep staging schedule (min latency cover = 4 MFMA phases):
//   t.P1: stage B-lo(t+1), B-hi(t+1)   [buf (t+1)&1 free since t-1.P3]
//   t.P4: stage A-lo(t+2), A-hi(t+2)   [A of buf t&1 dead after t.P3]
//   boundary: s_waitcnt vmcnt(4) — leaves t+2's A loads in flight, never
//   drains to 0 until the tail (t>=14). One wait per K-tile.
// Fragment reads / XOR chunk swizzle / MFMA order unchanged (bit-identical).
// ---------------------------------------------------------------------------
__global__ __launch_bounds__(512, 2) void k1_gemm_tanh(
    const u16* __restrict__ xb, const u16* __restrict__ hb,
    const u16* __restrict__ Wih, const u16* __restrict__ Whh,
    u16* __restrict__ Tb) {
  __shared__ u16 S[65536];   // [buf0: A 256x64 | B 256x64][buf1: A | B] = 128 KiB
  const int tid  = threadIdx.x;          // 0..511
  const int lane = tid & 63;
  const int w    = tid >> 6;             // 0..7
  const int wm   = w >> 2;               // 0..1  (M half)
  const int wn   = w & 3;                // 0..3  (N quarter)
  const int quad = lane >> 4, rl = lane & 15, l7 = lane & 7;
  const int sr   = tid >> 3;             // 0..63 staging row-in-pass
  const int sc   = ((tid & 7) ^ (sr & 7)) * 8;   // swizzled source chunk

  // XCD-chunked bijective swizzle: 256 wg = 8 XCD x 32; each XCD gets 2 B-panels
  const int wg  = blockIdx.x;
  const int lin = ((wg & 7) << 5) | (wg >> 3);
  const int bx  = lin & 15;
  const int by  = lin >> 4;
  const int row0 = bx * 256;
  const int col0 = by * 256;             // j = k*512 + n; 256 | 512 -> single-k tile
  const int kk   = col0 >> 9;
  const int nh0  = col0 & 511;

  const u16* const As2[2] = { xb, hb };
  const u16* const Bs2[2] = { Wih + (size_t)kk * 262144, Whh + (size_t)kk * 262144 };

  // region: 0=A-lo 1=A-hi 2=B-lo 3=B-hi (half = 128 rows); 2 x gload16/thread
  auto stage = [&](int tile, int region) {
    if (tile >= 16) return;
    const int g    = tile >> 3;          // 0: x/Wih, 1: h/Whh
    const int ko   = (tile & 7) * 64;
    const int isB  = region >> 1;
    const int half = region & 1;
    const u16* src = isB ? Bs2[g] : As2[g];
    const int r0   = (isB ? nh0 : row0) + half * 128;
    u16* dst = S + (tile & 1) * 32768 + isB * 16384 + half * 8192;
    const u16* s0 = src + (size_t)(r0 + sr) * 512 + ko + sc;
    gload16(s0,            dst + tid * 8);
    gload16(s0 + 64 * 512, dst + 4096 + tid * 8);
  };

  auto ldA = [&](int buf, int mi, int ks) -> short8 {
    return *(const short8*)&S[buf * 32768 +
                              (wm * 128 + mi * 16 + rl) * 64 +
                              ((ks * 4 + quad) ^ l7) * 8];
  };
  auto ldB = [&](int buf, int j, int ks) -> short8 {
    return *(const short8*)&S[buf * 32768 + 16384 +
                              (wn * 64 + j * 16 + rl) * 64 +
                              ((ks * 4 + quad) ^ l7) * 8];
  };

  f32x4 acc[8][4] = {};
  short8 af[4][2], bf[4][2];

  // prologue: tile0 fully + A-lo/A-hi of tile1 in flight behind it
  stage(0, 0); stage(0, 1); stage(0, 2); stage(0, 3);
  stage(1, 0); stage(1, 1);
  asm volatile("s_waitcnt vmcnt(4)" ::: "memory");   // tile0 resident
  __builtin_amdgcn_s_barrier();

#pragma unroll 1
  for (int t = 0; t < 16; ++t) {
    const int buf = t & 1;

    // ---- P1: Q0 = m0-3 x n0-1  (12 ds_reads) + stage B(t+1)
#pragma unroll
    for (int m = 0; m < 4; ++m) { af[m][0] = ldA(buf, m, 0); af[m][1] = ldA(buf, m, 1); }
#pragma unroll
    for (int j = 0; j < 2; ++j) { bf[j][0] = ldB(buf, j, 0); bf[j][1] = ldB(buf, j, 1); }
    stage(t + 1, 2);
    stage(t + 1, 3);
    __builtin_amdgcn_s_barrier();
    asm volatile("s_waitcnt lgkmcnt(0)" ::: "memory");
    __builtin_amdgcn_s_setprio(1);
#pragma unroll
    for (int m = 0; m < 4; ++m)
#pragma unroll
      for (int n = 0; n < 2; ++n)
#pragma unroll
        for (int ks = 0; ks < 2; ++ks)
          acc[m][n] = __builtin_amdgcn_mfma_f32_16x16x32_bf16(af[m][ks], bf[n][ks], acc[m][n], 0, 0, 0);
    __builtin_amdgcn_s_setprio(0);
    __builtin_amdgcn_s_barrier();

    // ---- P2: Q1 = m0-3 x n2-3  (4 ds_reads; af reused)
#pragma unroll
    for (int j = 2; j < 4; ++j) { bf[j][0] = ldB(buf, j, 0); bf[j][1] = ldB(buf, j, 1); }
    __builtin_amdgcn_s_barrier();
    asm volatile("s_waitcnt lgkmcnt(0)" ::: "memory");
    __builtin_amdgcn_s_setprio(1);
#pragma unroll
    for (int m = 0; m < 4; ++m)
#pragma unroll
      for (int n = 2; n < 4; ++n)
#pragma unroll
        for (int ks = 0; ks < 2; ++ks)
          acc[m][n] = __builtin_amdgcn_mfma_f32_16x16x32_bf16(af[m][ks], bf[n][ks], acc[m][n], 0, 0, 0);
    __builtin_amdgcn_s_setprio(0);
    __builtin_amdgcn_s_barrier();

    // ---- P3: Q2 = m4-7 x n2-3  (8 ds_reads; bf reused)
#pragma unroll
    for (int m = 0; m < 4; ++m) { af[m][0] = ldA(buf, 4 + m, 0); af[m][1] = ldA(buf, 4 + m, 1); }
    __builtin_amdgcn_s_barrier();
    asm volatile("s_waitcnt lgkmcnt(0)" ::: "memory");
    __builtin_amdgcn_s_setprio(1);
#pragma unroll
    for (int m = 0; m < 4; ++m)
#pragma unroll
      for (int n = 2; n < 4; ++n)
#pragma unroll
        for (int ks = 0; ks < 2; ++ks)
          acc[4 + m][n] = __builtin_amdgcn_mfma_f32_16x16x32_bf16(af[m][ks], bf[n][ks], acc[4 + m][n], 0, 0, 0);
    __builtin_amdgcn_s_setprio(0);
    __builtin_amdgcn_s_barrier();

    // ---- P4: Q3 = m4-7 x n0-1  (0 ds_reads) + stage A(t+2) + boundary vmcnt
    stage(t + 2, 0);
    stage(t + 2, 1);
    __builtin_amdgcn_s_barrier();
    __builtin_amdgcn_s_setprio(1);
#pragma unroll
    for (int m = 0; m < 4; ++m)
#pragma unroll
      for (int n = 0; n < 2; ++n)
#pragma unroll
        for (int ks = 0; ks < 2; ++ks)
          acc[4 + m][n] = __builtin_amdgcn_mfma_f32_16x16x32_bf16(af[m][ks], bf[n][ks], acc[4 + m][n], 0, 0, 0);
    __builtin_amdgcn_s_setprio(0);
    // leave only t+2's A loads (issued this phase) in flight
    if (t < 14) asm volatile("s_waitcnt vmcnt(4)" ::: "memory");
    else        asm volatile("s_waitcnt vmcnt(0)" ::: "memory");
    __builtin_amdgcn_s_barrier();
  }

  // epilogue: tanh -> bf16 -> LDS transpose (stride 264 u16, 16B rows, 2 halves)
#pragma unroll 1
  for (int hp = 0; hp < 2; ++hp) {
    if (wm == hp) {
#pragma unroll
      for (int m = 0; m < 8; ++m)
#pragma unroll
        for (int n = 0; n < 4; ++n)
#pragma unroll
          for (int r = 0; r < 4; ++r) {
            const int lr = m * 16 + quad * 4 + r;       // row within half
            const float v = acc[m][n][r];
            const float e = __expf(2.0f * v);           // tanh, saturating, no NaN
            S[lr * 264 + wn * 64 + n * 16 + rl] = f2b(1.0f - 2.0f / (e + 1.0f));
          }
    }
    asm volatile("s_waitcnt lgkmcnt(0)" ::: "memory");  // drain ds_writes pre-barrier
    __builtin_amdgcn_s_barrier();
#pragma unroll
    for (int p = 0; p < 8; ++p) {
      const int idx = p * 512 + tid;    // 0..4095
      const int c = idx & 31, rr = idx >> 5;
      *(short8*)&Tb[(size_t)(row0 + hp * 128 + rr) * 4096 + col0 + c * 8] =
          *(const short8*)&S[rr * 264 + c * 8];
    }
    __builtin_amdgcn_s_barrier();
  }
}

// ---------------------------------------------------------------------------
// K2: Ob[b][k*256+y] = sum_n Tb[b][k*512+n] * Wout[y][n]   (8 batched GEMMs)
// bf16 in / bf16 out (plane in ws). Same structure + transpose epilogue.
// ---------------------------------------------------------------------------
__global__ __launch_bounds__(256) void k2_gemm_out(
    const u16* __restrict__ Tb, const u16* __restrict__ Wout,
    u16* __restrict__ Ob) {
  __shared__ u16 S[128 * 136];
  u16* As = S;
  u16* Bs = S + 128 * 64;
  const int tid  = threadIdx.x;
  const int lane = tid & 63;
  const int w    = tid >> 6;
  const int wm   = w >> 1, wn = w & 1;
  const int row0 = blockIdx.x * 128;
  const int y0   = blockIdx.y * 128;
  const int kk   = blockIdx.z;
  const int sr   = tid >> 3;
  const int sc   = ((tid & 7) ^ ((tid >> 3) & 7)) * 8;
  const int ldsw = (w * 8) * 64;

  f32x4 acc[4][4] = {};

  for (int kt = 0; kt < 8; ++kt) {
    const int kb = kt * 64;
#pragma unroll
    for (int ro = 0; ro < 4; ++ro) {
      gload16(Tb + (size_t)(row0 + ro * 32 + sr) * 4096 + kk * 512 + kb + sc,
              &As[ro * 32 * 64 + ldsw]);
      gload16(Wout + (size_t)(y0 + ro * 32 + sr) * 512 + kb + sc,
              &Bs[ro * 32 * 64 + ldsw]);
    }
    __syncthreads();
    const int l7 = lane & 7, quad = lane >> 4, rl = lane & 15;
#pragma unroll
    for (int ks = 0; ks < 2; ++ks) {
      short8 af[4], bf[4];
      const int cs = ((ks * 4 + quad) ^ l7) * 8;
#pragma unroll
      for (int i = 0; i < 4; ++i)
        af[i] = *(const short8*)&As[(wm * 64 + i * 16 + rl) * 64 + cs];
#pragma unroll
      for (int j = 0; j < 4; ++j)
        bf[j] = *(const short8*)&Bs[(wn * 64 + j * 16 + rl) * 64 + cs];
#pragma unroll
      for (int i = 0; i < 4; ++i)
#pragma unroll
        for (int j = 0; j < 4; ++j)
          acc[i][j] = __builtin_amdgcn_mfma_f32_16x16x32_bf16(af[i], bf[j], acc[i][j], 0, 0, 0);
    }
    __syncthreads();
  }

  const int quad = lane >> 4, cl = lane & 15;
#pragma unroll
  for (int i = 0; i < 4; ++i)
#pragma unroll
    for (int j = 0; j < 4; ++j)
#pragma unroll
      for (int r = 0; r < 4; ++r) {
        const int row = wm * 64 + i * 16 + quad * 4 + r;
        const int col = wn * 64 + j * 16 + cl;
        S[row * 136 + col] = f2b(acc[i][j][r]);
      }
  __syncthreads();
#pragma unroll
  for (int it = 0; it < 8; ++it) {
    const int idx = it * 256 + tid;
    const int c = idx & 15;
    const int r = idx >> 4;
    *(short8*)&Ob[(size_t)(row0 + r) * 2048 + kk * 256 + y0 + c * 8] =
        *(const short8*)&S[r * 136 + c * 8];
  }
}

// ---------------------------------------------------------------------------
// K3: epilogue. Block b: reads Tb row + Ob row (bf16, ws), writes f32
// interleaved h_k / out_k (coalesced float4) + h_mix + out.
// ---------------------------------------------------------------------------
__global__ __launch_bounds__(512) void k3_epi(const float* __restrict__ pi,
                                              const u16* __restrict__ Tb,
                                              const u16* __restrict__ Ob,
                                              float* __restrict__ dout) {
  const int b   = blockIdx.x;
  const int tid = threadIdx.x;

  float pif[8];
#pragma unroll
  for (int k = 0; k < 8; ++k) pif[k] = pi[b * 8 + k];

  float tv[8]; float hm = 0.0f;
#pragma unroll
  for (int k = 0; k < 8; ++k) {
    const float v = b2f(Tb[(size_t)b * 4096 + k * 512 + tid]);
    tv[k] = v; hm += pif[k] * v;
  }
  float4* tw = (float4*)&dout[OFF_HK + (size_t)b * 4096 + tid * 8];
  tw[0] = make_float4(tv[0], tv[1], tv[2], tv[3]);
  tw[1] = make_float4(tv[4], tv[5], tv[6], tv[7]);
  dout[OFF_HMIX + (size_t)b * 512 + tid] = hm;

  if (tid < 256) {
    float ov[8]; float om = 0.0f;
#pragma unroll
    for (int k = 0; k < 8; ++k) {
      const float v = b2f(Ob[(size_t)b * 2048 + k * 256 + tid]);
      ov[k] = v; om += pif[k] * v;
    }
    float4* ow = (float4*)&dout[OFF_OK + (size_t)b * 2048 + tid * 8];
    ow[0] = make_float4(ov[0], ov[1], ov[2], ov[3]);
    ow[1] = make_float4(ov[4], ov[5], ov[6], ov[7]);
    dout[OFF_OUT + (size_t)b * 256 + tid] = om;
  }
}

extern "C" void kernel_launch(void* const* d_in, const int* in_sizes, int n_in,
                              void* d_out, int out_size, void* d_ws, size_t ws_size,
                              hipStream_t stream) {
  const float* x    = (const float*)d_in[0];
  const float* h    = (const float*)d_in[1];
  const float* pi   = (const float*)d_in[2];
  const float* Whh  = (const float*)d_in[4];
  const float* Wih  = (const float*)d_in[3];
  const float* Wout = (const float*)d_in[5];
  float* out = (float*)d_out;
  u16* ws  = (u16*)d_ws;

  k0_cvt<<<dim3(8320), 256, 0, stream>>>(x, h, Wih, Whh, Wout, ws);
  k1_gemm_tanh<<<dim3(256), 512, 0, stream>>>(
      ws + WS_XB, ws + WS_HB, ws + WS_WIH, ws + WS_WHH, ws + WS_T);
  k2_gemm_out<<<dim3(32, 2, 8), 256, 0, stream>>>(ws + WS_T, ws + WS_WOUT, ws + WS_OB);
  k3_epi<<<dim3(BATCH), 512, 0, stream>>>(pi, ws + WS_T, ws + WS_OB, out);
}

// Round 4
// 211.463 us; speedup vs baseline: 1.0426x; 1.0148x over previous
//
#include <hip/hip_runtime.h>
#include <hip/hip_bf16.h>
#include <stdint.h>

typedef unsigned short u16;
typedef __attribute__((ext_vector_type(8))) short short8;
typedef __attribute__((ext_vector_type(4))) float f32x4;

#define BATCH 4096
// output region offsets (f32 elements) in d_out: out, h_mix, out_k, h_k
#define OFF_OUT  0
#define OFF_HMIX (BATCH * 256)
#define OFF_OK   (OFF_HMIX + BATCH * 512)
#define OFF_HK   (OFF_OK + BATCH * 256 * 8)

// ws layout (u16/bf16 elements): xb, hb, Wihb, Whhb, Woutb, Tb, Ob (~67 MB)
#define WS_XB   0
#define WS_HB   (2097152)
#define WS_WIH  (4194304)
#define WS_WHH  (6291456)
#define WS_WOUT (8388608)
#define WS_T    (8519680)    // 4096x4096 bf16 plane
#define WS_OB   (25296896)   // 4096x2048 bf16 plane

__device__ __forceinline__ float b2f(u16 v) {
  union { uint32_t u; float f; } c; c.u = ((uint32_t)v) << 16; return c.f;
}
__device__ __forceinline__ u16 f2b(float f) {
  union { float f; uint32_t u; } c; c.f = f;
  uint32_t u = c.u;
  return (u16)((u + 0x7fffu + ((u >> 16) & 1u)) >> 16);  // RNE
}

// async global->LDS, 16B per lane. LDS dest = wave-uniform base + lane*16.
__device__ __forceinline__ void gload16(const u16* g, u16* l) {
  __builtin_amdgcn_global_load_lds(
      (const __attribute__((address_space(1))) void*)g,
      (__attribute__((address_space(3))) void*)l, 16, 0, 0);
}

// ---------------------------------------------------------------------------
// K0: f32 -> bf16 conversion of x, h, W_ih, W_hh, W_out into ws.
// ---------------------------------------------------------------------------
__global__ __launch_bounds__(256) void k0_cvt(
    const float* __restrict__ x, const float* __restrict__ h,
    const float* __restrict__ Wih, const float* __restrict__ Whh,
    const float* __restrict__ Wout, u16* __restrict__ ws) {
  const int i = blockIdx.x * 256 + threadIdx.x;
  const float* src; int j; size_t dst;
  if      (i <  524288) { src = x;    j = i;           dst = WS_XB;   }
  else if (i < 1048576) { src = h;    j = i -  524288; dst = WS_HB;   }
  else if (i < 1572864) { src = Wih;  j = i - 1048576; dst = WS_WIH;  }
  else if (i < 2097152) { src = Whh;  j = i - 1572864; dst = WS_WHH;  }
  else                  { src = Wout; j = i - 2097152; dst = WS_WOUT; }
  const float4 v = ((const float4*)src)[j];
  ushort4 o;
  o.x = f2b(v.x); o.y = f2b(v.y); o.z = f2b(v.z); o.w = f2b(v.w);
  ((ushort4*)(ws + dst))[j] = o;
}

// ---------------------------------------------------------------------------
// K1: Tb[b][k*512+n] = tanh( x[b]·W_ih[k][n] + h[b]·W_hh[k][n] )  (bf16 plane)
// 4096x4096x1024 bf16 GEMM, tanh epilogue.
// 256x256 tile, BK=64, 8 waves (2Mx4N, 128x64 per wave), double-buffered
// 128 KiB LDS, XCD-chunked block swizzle.
//
// FREE-RUN schedule: only TWO barriers per K-tile (the correctness-critical
// ones); waves self-schedule so ds_read (LDS pipe) overlaps sibling-wave
// MFMA (matrix pipe), and the compiler emits fine-grained lgkmcnt for the
// register deps instead of blanket drains.
//   R1: 16 ds_reads (af-lo, all bf) + stage B(t+1)         [+4 vm -> 8]
//   Q0+Q1: 32 MFMA (m0-3 x n0-3)
//   R2: 8 ds_reads (af-hi)
//   Q2: 16 MFMA (m4-7 x n2-3)
//   lgkmcnt(0); BARRIER-1   <- A-region of current buf now dead (all waves)
//   stage A(t+2)                                            [+4 vm -> 12]
//   Q3: 16 MFMA (m4-7 x n0-1, registers only)
//   vmcnt(4); BARRIER-2; fence   <- tile t+1 fully resident, A(t+2) in flight
// Hazards: B(t+1) overwrite of buf^1 covered by t-1's BARRIER-2 (bf reads
// drained at t-1's lgkm(0)); A(t+2) overwrite covered by BARRIER-1; t+1
// reads gated by own-vmcnt + BARRIER-2 + compiler fence (no load hoisting).
// Per-acc-element (t,ks) accumulation order unchanged -> bit-identical.
// ---------------------------------------------------------------------------
__global__ __launch_bounds__(512, 2) void k1_gemm_tanh(
    const u16* __restrict__ xb, const u16* __restrict__ hb,
    const u16* __restrict__ Wih, const u16* __restrict__ Whh,
    u16* __restrict__ Tb) {
  __shared__ u16 S[65536];   // [buf0: A 256x64 | B 256x64][buf1: A | B] = 128 KiB
  const int tid  = threadIdx.x;          // 0..511
  const int lane = tid & 63;
  const int w    = tid >> 6;             // 0..7
  const int wm   = w >> 2;               // 0..1  (M half)
  const int wn   = w & 3;                // 0..3  (N quarter)
  const int quad = lane >> 4, rl = lane & 15, l7 = lane & 7;
  const int sr   = tid >> 3;             // 0..63 staging row-in-pass
  const int sc   = ((tid & 7) ^ (sr & 7)) * 8;   // swizzled source chunk

  // XCD-chunked bijective swizzle: 256 wg = 8 XCD x 32; each XCD gets 2 B-panels
  const int wg  = blockIdx.x;
  const int lin = ((wg & 7) << 5) | (wg >> 3);
  const int bx  = lin & 15;
  const int by  = lin >> 4;
  const int row0 = bx * 256;
  const int col0 = by * 256;             // j = k*512 + n; 256 | 512 -> single-k tile
  const int kk   = col0 >> 9;
  const int nh0  = col0 & 511;

  const u16* const As2[2] = { xb, hb };
  const u16* const Bs2[2] = { Wih + (size_t)kk * 262144, Whh + (size_t)kk * 262144 };

  // region: 0=A-lo 1=A-hi 2=B-lo 3=B-hi (half = 128 rows); 2 x gload16/thread
  auto stage = [&](int tile, int region) {
    if (tile >= 16) return;
    const int g    = tile >> 3;          // 0: x/Wih, 1: h/Whh
    const int ko   = (tile & 7) * 64;
    const int isB  = region >> 1;
    const int half = region & 1;
    const u16* src = isB ? Bs2[g] : As2[g];
    const int r0   = (isB ? nh0 : row0) + half * 128;
    u16* dst = S + (tile & 1) * 32768 + isB * 16384 + half * 8192;
    const u16* s0 = src + (size_t)(r0 + sr) * 512 + ko + sc;
    gload16(s0,            dst + tid * 8);
    gload16(s0 + 64 * 512, dst + 4096 + tid * 8);
  };

  auto ldA = [&](int buf, int mi, int ks) -> short8 {
    return *(const short8*)&S[buf * 32768 +
                              (wm * 128 + mi * 16 + rl) * 64 +
                              ((ks * 4 + quad) ^ l7) * 8];
  };
  auto ldB = [&](int buf, int j, int ks) -> short8 {
    return *(const short8*)&S[buf * 32768 + 16384 +
                              (wn * 64 + j * 16 + rl) * 64 +
                              ((ks * 4 + quad) ^ l7) * 8];
  };

  f32x4 acc[8][4] = {};

  // prologue: tile0 fully + A-lo/A-hi of tile1 in flight behind it
  stage(0, 0); stage(0, 1); stage(0, 2); stage(0, 3);
  stage(1, 0); stage(1, 1);
  asm volatile("s_waitcnt vmcnt(4)" ::: "memory");   // tile0 resident
  __builtin_amdgcn_s_barrier();
  asm volatile("" ::: "memory");

#pragma unroll 1
  for (int t = 0; t < 16; ++t) {
    const int buf = t & 1;
    short8 al[4][2], ah[4][2], bf[4][2];

    // ---- R1: af-lo + all bf (16 ds_reads) + stage B(t+1)
#pragma unroll
    for (int m = 0; m < 4; ++m) { al[m][0] = ldA(buf, m, 0); al[m][1] = ldA(buf, m, 1); }
#pragma unroll
    for (int j = 0; j < 4; ++j) { bf[j][0] = ldB(buf, j, 0); bf[j][1] = ldB(buf, j, 1); }
    stage(t + 1, 2);
    stage(t + 1, 3);

    // ---- Q0+Q1: m0-3 x n0-3 (compiler inserts precise lgkmcnt waits)
    __builtin_amdgcn_s_setprio(1);
#pragma unroll
    for (int m = 0; m < 4; ++m)
#pragma unroll
      for (int n = 0; n < 4; ++n)
#pragma unroll
        for (int ks = 0; ks < 2; ++ks)
          acc[m][n] = __builtin_amdgcn_mfma_f32_16x16x32_bf16(al[m][ks], bf[n][ks], acc[m][n], 0, 0, 0);
    __builtin_amdgcn_s_setprio(0);

    // ---- R2: af-hi (8 ds_reads)
#pragma unroll
    for (int m = 0; m < 4; ++m) { ah[m][0] = ldA(buf, 4 + m, 0); ah[m][1] = ldA(buf, 4 + m, 1); }

    // ---- Q2: m4-7 x n2-3
    __builtin_amdgcn_s_setprio(1);
#pragma unroll
    for (int m = 0; m < 4; ++m)
#pragma unroll
      for (int n = 2; n < 4; ++n)
#pragma unroll
        for (int ks = 0; ks < 2; ++ks)
          acc[4 + m][n] = __builtin_amdgcn_mfma_f32_16x16x32_bf16(ah[m][ks], bf[n][ks], acc[4 + m][n], 0, 0, 0);
    __builtin_amdgcn_s_setprio(0);

    // ---- BARRIER-1: A-region of buf now dead across all waves
    asm volatile("s_waitcnt lgkmcnt(0)" ::: "memory");
    __builtin_amdgcn_s_barrier();
    stage(t + 2, 0);
    stage(t + 2, 1);

    // ---- Q3: m4-7 x n0-1 (registers only)
    __builtin_amdgcn_s_setprio(1);
#pragma unroll
    for (int m = 0; m < 4; ++m)
#pragma unroll
      for (int n = 0; n < 2; ++n)
#pragma unroll
        for (int ks = 0; ks < 2; ++ks)
          acc[4 + m][n] = __builtin_amdgcn_mfma_f32_16x16x32_bf16(ah[m][ks], bf[n][ks], acc[4 + m][n], 0, 0, 0);
    __builtin_amdgcn_s_setprio(0);

    // ---- BARRIER-2: tile boundary. Leave only A(t+2)'s 4 loads in flight.
    if (t < 14) asm volatile("s_waitcnt vmcnt(4)" ::: "memory");
    else        asm volatile("s_waitcnt vmcnt(0)" ::: "memory");
    __builtin_amdgcn_s_barrier();
    asm volatile("" ::: "memory");     // fence: no t+1 ds_read hoists above
  }

  // epilogue: tanh -> bf16 -> LDS transpose (stride 264 u16, 16B rows, 2 halves)
#pragma unroll 1
  for (int hp = 0; hp < 2; ++hp) {
    if (wm == hp) {
#pragma unroll
      for (int m = 0; m < 8; ++m)
#pragma unroll
        for (int n = 0; n < 4; ++n)
#pragma unroll
          for (int r = 0; r < 4; ++r) {
            const int lr = m * 16 + quad * 4 + r;       // row within half
            const float v = acc[m][n][r];
            const float e = __expf(2.0f * v);           // tanh, saturating, no NaN
            S[lr * 264 + wn * 64 + n * 16 + rl] = f2b(1.0f - 2.0f / (e + 1.0f));
          }
    }
    asm volatile("s_waitcnt lgkmcnt(0)" ::: "memory");  // drain ds_writes pre-barrier
    __builtin_amdgcn_s_barrier();
#pragma unroll
    for (int p = 0; p < 8; ++p) {
      const int idx = p * 512 + tid;    // 0..4095
      const int c = idx & 31, rr = idx >> 5;
      *(short8*)&Tb[(size_t)(row0 + hp * 128 + rr) * 4096 + col0 + c * 8] =
          *(const short8*)&S[rr * 264 + c * 8];
    }
    __builtin_amdgcn_s_barrier();
  }
}

// ---------------------------------------------------------------------------
// K2: Ob[b][k*256+y] = sum_n Tb[b][k*512+n] * Wout[y][n]   (8 batched GEMMs)
// bf16 in / bf16 out (plane in ws). Same structure + transpose epilogue.
// ---------------------------------------------------------------------------
__global__ __launch_bounds__(256) void k2_gemm_out(
    const u16* __restrict__ Tb, const u16* __restrict__ Wout,
    u16* __restrict__ Ob) {
  __shared__ u16 S[128 * 136];
  u16* As = S;
  u16* Bs = S + 128 * 64;
  const int tid  = threadIdx.x;
  const int lane = tid & 63;
  const int w    = tid >> 6;
  const int wm   = w >> 1, wn = w & 1;
  const int row0 = blockIdx.x * 128;
  const int y0   = blockIdx.y * 128;
  const int kk   = blockIdx.z;
  const int sr   = tid >> 3;
  const int sc   = ((tid & 7) ^ ((tid >> 3) & 7)) * 8;
  const int ldsw = (w * 8) * 64;

  f32x4 acc[4][4] = {};

  for (int kt = 0; kt < 8; ++kt) {
    const int kb = kt * 64;
#pragma unroll
    for (int ro = 0; ro < 4; ++ro) {
      gload16(Tb + (size_t)(row0 + ro * 32 + sr) * 4096 + kk * 512 + kb + sc,
              &As[ro * 32 * 64 + ldsw]);
      gload16(Wout + (size_t)(y0 + ro * 32 + sr) * 512 + kb + sc,
              &Bs[ro * 32 * 64 + ldsw]);
    }
    __syncthreads();
    const int l7 = lane & 7, quad = lane >> 4, rl = lane & 15;
#pragma unroll
    for (int ks = 0; ks < 2; ++ks) {
      short8 af[4], bf[4];
      const int cs = ((ks * 4 + quad) ^ l7) * 8;
#pragma unroll
      for (int i = 0; i < 4; ++i)
        af[i] = *(const short8*)&As[(wm * 64 + i * 16 + rl) * 64 + cs];
#pragma unroll
      for (int j = 0; j < 4; ++j)
        bf[j] = *(const short8*)&Bs[(wn * 64 + j * 16 + rl) * 64 + cs];
#pragma unroll
      for (int i = 0; i < 4; ++i)
#pragma unroll
        for (int j = 0; j < 4; ++j)
          acc[i][j] = __builtin_amdgcn_mfma_f32_16x16x32_bf16(af[i], bf[j], acc[i][j], 0, 0, 0);
    }
    __syncthreads();
  }

  const int quad = lane >> 4, cl = lane & 15;
#pragma unroll
  for (int i = 0; i < 4; ++i)
#pragma unroll
    for (int j = 0; j < 4; ++j)
#pragma unroll
      for (int r = 0; r < 4; ++r) {
        const int row = wm * 64 + i * 16 + quad * 4 + r;
        const int col = wn * 64 + j * 16 + cl;
        S[row * 136 + col] = f2b(acc[i][j][r]);
      }
  __syncthreads();
#pragma unroll
  for (int it = 0; it < 8; ++it) {
    const int idx = it * 256 + tid;
    const int c = idx & 15;
    const int r = idx >> 4;
    *(short8*)&Ob[(size_t)(row0 + r) * 2048 + kk * 256 + y0 + c * 8] =
        *(const short8*)&S[r * 136 + c * 8];
  }
}

// ---------------------------------------------------------------------------
// K3: epilogue. Block b: reads Tb row + Ob row (bf16, ws), writes f32
// interleaved h_k / out_k (coalesced float4) + h_mix + out.
// ---------------------------------------------------------------------------
__global__ __launch_bounds__(512) void k3_epi(const float* __restrict__ pi,
                                              const u16* __restrict__ Tb,
                                              const u16* __restrict__ Ob,
                                              float* __restrict__ dout) {
  const int b   = blockIdx.x;
  const int tid = threadIdx.x;

  float pif[8];
#pragma unroll
  for (int k = 0; k < 8; ++k) pif[k] = pi[b * 8 + k];

  float tv[8]; float hm = 0.0f;
#pragma unroll
  for (int k = 0; k < 8; ++k) {
    const float v = b2f(Tb[(size_t)b * 4096 + k * 512 + tid]);
    tv[k] = v; hm += pif[k] * v;
  }
  float4* tw = (float4*)&dout[OFF_HK + (size_t)b * 4096 + tid * 8];
  tw[0] = make_float4(tv[0], tv[1], tv[2], tv[3]);
  tw[1] = make_float4(tv[4], tv[5], tv[6], tv[7]);
  dout[OFF_HMIX + (size_t)b * 512 + tid] = hm;

  if (tid < 256) {
    float ov[8]; float om = 0.0f;
#pragma unroll
    for (int k = 0; k < 8; ++k) {
      const float v = b2f(Ob[(size_t)b * 2048 + k * 256 + tid]);
      ov[k] = v; om += pif[k] * v;
    }
    float4* ow = (float4*)&dout[OFF_OK + (size_t)b * 2048 + tid * 8];
    ow[0] = make_float4(ov[0], ov[1], ov[2], ov[3]);
    ow[1] = make_float4(ov[4], ov[5], ov[6], ov[7]);
    dout[OFF_OUT + (size_t)b * 256 + tid] = om;
  }
}

extern "C" void kernel_launch(void* const* d_in, const int* in_sizes, int n_in,
                              void* d_out, int out_size, void* d_ws, size_t ws_size,
                              hipStream_t stream) {
  const float* x    = (const float*)d_in[0];
  const float* h    = (const float*)d_in[1];
  const float* pi   = (const float*)d_in[2];
  const float* Wih  = (const float*)d_in[3];
  const float* Whh  = (const float*)d_in[4];
  const float* Wout = (const float*)d_in[5];
  float* out = (float*)d_out;
  u16* ws  = (u16*)d_ws;

  k0_cvt<<<dim3(8320), 256, 0, stream>>>(x, h, Wih, Whh, Wout, ws);
  k1_gemm_tanh<<<dim3(256), 512, 0, stream>>>(
      ws + WS_XB, ws + WS_HB, ws + WS_WIH, ws + WS_WHH, ws + WS_T);
  k2_gemm_out<<<dim3(32, 2, 8), 256, 0, stream>>>(ws + WS_T, ws + WS_WOUT, ws + WS_OB);
  k3_epi<<<dim3(BATCH), 512, 0, stream>>>(pi, ws + WS_T, ws + WS_OB, out);
}

// Round 5
// 209.438 us; speedup vs baseline: 1.0527x; 1.0097x over previous
//
#include <hip/hip_runtime.h>
#include <hip/hip_bf16.h>
#include <stdint.h>

typedef unsigned short u16;
typedef __attribute__((ext_vector_type(8))) short short8;
typedef __attribute__((ext_vector_type(4))) float f32x4;

#define BATCH 4096
// output region offsets (f32 elements) in d_out: out, h_mix, out_k, h_k
#define OFF_OUT  0
#define OFF_HMIX (BATCH * 256)
#define OFF_OK   (OFF_HMIX + BATCH * 512)
#define OFF_HK   (OFF_OK + BATCH * 256 * 8)

// ws layout (u16/bf16 elements): xb, hb, Wihb, Whhb, Woutb, Tb, Ob (~67 MB)
#define WS_XB   0
#define WS_HB   (2097152)
#define WS_WIH  (4194304)
#define WS_WHH  (6291456)
#define WS_WOUT (8388608)
#define WS_T    (8519680)    // 4096x4096 bf16 plane
#define WS_OB   (25296896)   // 4096x2048 bf16 plane

__device__ __forceinline__ float b2f(u16 v) {
  union { uint32_t u; float f; } c; c.u = ((uint32_t)v) << 16; return c.f;
}
__device__ __forceinline__ u16 f2b(float f) {
  union { float f; uint32_t u; } c; c.f = f;
  uint32_t u = c.u;
  return (u16)((u + 0x7fffu + ((u >> 16) & 1u)) >> 16);  // RNE
}

// async global->LDS, 16B per lane. LDS dest = wave-uniform base + lane*16.
__device__ __forceinline__ void gload16(const u16* g, u16* l) {
  __builtin_amdgcn_global_load_lds(
      (const __attribute__((address_space(1))) void*)g,
      (__attribute__((address_space(3))) void*)l, 16, 0, 0);
}

// ---------------------------------------------------------------------------
// K0: f32 -> bf16 conversion of x, h, W_ih, W_hh, W_out into ws.
// ---------------------------------------------------------------------------
__global__ __launch_bounds__(256) void k0_cvt(
    const float* __restrict__ x, const float* __restrict__ h,
    const float* __restrict__ Wih, const float* __restrict__ Whh,
    const float* __restrict__ Wout, u16* __restrict__ ws) {
  const int i = blockIdx.x * 256 + threadIdx.x;
  const float* src; int j; size_t dst;
  if      (i <  524288) { src = x;    j = i;           dst = WS_XB;   }
  else if (i < 1048576) { src = h;    j = i -  524288; dst = WS_HB;   }
  else if (i < 1572864) { src = Wih;  j = i - 1048576; dst = WS_WIH;  }
  else if (i < 2097152) { src = Whh;  j = i - 1572864; dst = WS_WHH;  }
  else                  { src = Wout; j = i - 2097152; dst = WS_WOUT; }
  const float4 v = ((const float4*)src)[j];
  ushort4 o;
  o.x = f2b(v.x); o.y = f2b(v.y); o.z = f2b(v.z); o.w = f2b(v.w);
  ((ushort4*)(ws + dst))[j] = o;
}

// ---------------------------------------------------------------------------
// K1: Tb[b][k*512+n] = tanh( x[b]·W_ih[k][n] + h[b]·W_hh[k][n] )  (bf16 plane)
// 4096x4096x1024 bf16 GEMM, tanh epilogue.
// 256x256 tile, BK=64, 8 waves (2Mx4N, 128x64 per wave), double-buffered
// 128 KiB LDS, XCD-chunked block swizzle.
//
// PIPELINED schedule: every MFMA cluster's ds_reads are issued ONE CLUSTER
// AHEAD (m201's read-ahead), so each read gets ~1 cluster (16 MFMA) of
// latency cover. Boundary vmcnt+barrier moved BEFORE C3 (register-only), so
// next-tile al/bl reads are covered by C3. No setprio (m190: hurts
// non-phase-split GEMM). 2 barriers/tile.
//   per tile t (buf = t&1):
//     issue bh(buf)[4]  | stage B(t+1)          -> C0: al x BLc (m0-3,n0-1)
//     issue ah(buf)[8]                          -> C1: al x bh  (m0-3,n2-3)
//     lgkm(0); B1  [A-region dead block-wide]
//     stage A(t+2)                              -> C2: ah x bh  (m4-7,n2-3)
//     vmcnt(4|0); B2  [buf^1 resident; A(t+2) in flight]
//     issue al(buf^1)[8] + BLn(buf^1)[4]        -> C3: ah x BLc (m4-7,n0-1)
// Ledger: enter t with 4 (A(t+1)); +4 B(t+1) = 8; +4 A(t+2) = 12; vmcnt(4)
// drains A(t+1)+B(t+1). Tail t>=14: vmcnt(0), stage()s are no-ops.
// al dead after C1 -> reloaded in place at tile end; bl double-buffered.
// Per-acc-element (t,ks) order unchanged -> bit-identical results.
// ---------------------------------------------------------------------------
__global__ __launch_bounds__(512, 2) void k1_gemm_tanh(
    const u16* __restrict__ xb, const u16* __restrict__ hb,
    const u16* __restrict__ Wih, const u16* __restrict__ Whh,
    u16* __restrict__ Tb) {
  __shared__ u16 S[65536];   // [buf0: A 256x64 | B 256x64][buf1: A | B] = 128 KiB
  const int tid  = threadIdx.x;          // 0..511
  const int lane = tid & 63;
  const int w    = tid >> 6;             // 0..7
  const int wm   = w >> 2;               // 0..1  (M half)
  const int wn   = w & 3;                // 0..3  (N quarter)
  const int quad = lane >> 4, rl = lane & 15, l7 = lane & 7;
  const int sr   = tid >> 3;             // 0..63 staging row-in-pass
  const int sc   = ((tid & 7) ^ (sr & 7)) * 8;   // swizzled source chunk

  // XCD-chunked bijective swizzle: 256 wg = 8 XCD x 32; each XCD gets 2 B-panels
  const int wg  = blockIdx.x;
  const int lin = ((wg & 7) << 5) | (wg >> 3);
  const int bx  = lin & 15;
  const int by  = lin >> 4;
  const int row0 = bx * 256;
  const int col0 = by * 256;             // j = k*512 + n; 256 | 512 -> single-k tile
  const int kk   = col0 >> 9;
  const int nh0  = col0 & 511;

  const u16* const As2[2] = { xb, hb };
  const u16* const Bs2[2] = { Wih + (size_t)kk * 262144, Whh + (size_t)kk * 262144 };

  // region: 0=A-lo 1=A-hi 2=B-lo 3=B-hi (half = 128 rows); 2 x gload16/thread
  auto stage = [&](int tile, int region) {
    if (tile >= 16) return;
    const int g    = tile >> 3;          // 0: x/Wih, 1: h/Whh
    const int ko   = (tile & 7) * 64;
    const int isB  = region >> 1;
    const int half = region & 1;
    const u16* src = isB ? Bs2[g] : As2[g];
    const int r0   = (isB ? nh0 : row0) + half * 128;
    u16* dst = S + (tile & 1) * 32768 + isB * 16384 + half * 8192;
    const u16* s0 = src + (size_t)(r0 + sr) * 512 + ko + sc;
    gload16(s0,            dst + tid * 8);
    gload16(s0 + 64 * 512, dst + 4096 + tid * 8);
  };

  auto ldA = [&](int buf, int mi, int ks) -> short8 {
    return *(const short8*)&S[buf * 32768 +
                              (wm * 128 + mi * 16 + rl) * 64 +
                              ((ks * 4 + quad) ^ l7) * 8];
  };
  auto ldB = [&](int buf, int j, int ks) -> short8 {
    return *(const short8*)&S[buf * 32768 + 16384 +
                              (wn * 64 + j * 16 + rl) * 64 +
                              ((ks * 4 + quad) ^ l7) * 8];
  };

  f32x4 acc[8][4] = {};
  short8 al[4][2], ah[4][2], bh[2][2], blA[2][2], blB[2][2];

  // prologue: tile0 fully + A-lo/A-hi of tile1 in flight behind it
  stage(0, 0); stage(0, 1); stage(0, 2); stage(0, 3);
  stage(1, 0); stage(1, 1);
  asm volatile("s_waitcnt vmcnt(4)" ::: "memory");   // tile0 resident
  __builtin_amdgcn_s_barrier();
  asm volatile("" ::: "memory");
  // pre-load tile0 fragments (al + blA)
#pragma unroll
  for (int m = 0; m < 4; ++m) { al[m][0] = ldA(0, m, 0); al[m][1] = ldA(0, m, 1); }
#pragma unroll
  for (int j = 0; j < 2; ++j) { blA[j][0] = ldB(0, j, 0); blA[j][1] = ldB(0, j, 1); }

#define TILE_BODY(T, BUF, BLc, BLn)                                            \
  {                                                                            \
    /* bh reads (for C1) + stage B(T+1) */                                     \
    _Pragma("unroll")                                                          \
    for (int j = 0; j < 2; ++j) {                                              \
      bh[j][0] = ldB(BUF, 2 + j, 0); bh[j][1] = ldB(BUF, 2 + j, 1);            \
    }                                                                          \
    stage((T) + 1, 2); stage((T) + 1, 3);                                      \
    /* C0: m0-3 x n0-1 (al, BLc pre-loaded last tile) */                       \
    _Pragma("unroll")                                                          \
    for (int m = 0; m < 4; ++m)                                                \
      _Pragma("unroll")                                                        \
      for (int n = 0; n < 2; ++n)                                              \
        _Pragma("unroll")                                                      \
        for (int ks = 0; ks < 2; ++ks)                                         \
          acc[m][n] = __builtin_amdgcn_mfma_f32_16x16x32_bf16(                 \
              al[m][ks], BLc[n][ks], acc[m][n], 0, 0, 0);                      \
    /* ah reads (for C2) */                                                    \
    _Pragma("unroll")                                                          \
    for (int m = 0; m < 4; ++m) {                                              \
      ah[m][0] = ldA(BUF, 4 + m, 0); ah[m][1] = ldA(BUF, 4 + m, 1);            \
    }                                                                          \
    /* C1: m0-3 x n2-3 */                                                      \
    _Pragma("unroll")                                                          \
    for (int m = 0; m < 4; ++m)                                                \
      _Pragma("unroll")                                                        \
      for (int n = 0; n < 2; ++n)                                              \
        _Pragma("unroll")                                                      \
        for (int ks = 0; ks < 2; ++ks)                                         \
          acc[m][2 + n] = __builtin_amdgcn_mfma_f32_16x16x32_bf16(             \
              al[m][ks], bh[n][ks], acc[m][2 + n], 0, 0, 0);                   \
    /* B1: A-region of buf dead block-wide */                                  \
    asm volatile("s_waitcnt lgkmcnt(0)" ::: "memory");                         \
    __builtin_amdgcn_s_barrier();                                              \
    stage((T) + 2, 0); stage((T) + 2, 1);                                      \
    /* C2: m4-7 x n2-3 */                                                      \
    _Pragma("unroll")                                                          \
    for (int m = 0; m < 4; ++m)                                                \
      _Pragma("unroll")                                                        \
      for (int n = 0; n < 2; ++n)                                              \
        _Pragma("unroll")                                                      \
        for (int ks = 0; ks < 2; ++ks)                                         \
          acc[4 + m][2 + n] = __builtin_amdgcn_mfma_f32_16x16x32_bf16(         \
              ah[m][ks], bh[n][ks], acc[4 + m][2 + n], 0, 0, 0);               \
    /* B2: tile boundary; leave only A(T+2)'s 4 loads in flight */             \
    if ((T) < 14) asm volatile("s_waitcnt vmcnt(4)" ::: "memory");             \
    else          asm volatile("s_waitcnt vmcnt(0)" ::: "memory");             \
    __builtin_amdgcn_s_barrier();                                              \
    asm volatile("" ::: "memory");                                             \
    /* next-tile reads from buf^1, covered by C3 (garbage-safe at T==15) */    \
    _Pragma("unroll")                                                          \
    for (int m = 0; m < 4; ++m) {                                              \
      al[m][0] = ldA(1 - (BUF), m, 0); al[m][1] = ldA(1 - (BUF), m, 1);        \
    }                                                                          \
    _Pragma("unroll")                                                          \
    for (int j = 0; j < 2; ++j) {                                              \
      BLn[j][0] = ldB(1 - (BUF), j, 0); BLn[j][1] = ldB(1 - (BUF), j, 1);      \
    }                                                                          \
    /* C3: m4-7 x n0-1 (registers only) */                                     \
    _Pragma("unroll")                                                          \
    for (int m = 0; m < 4; ++m)                                                \
      _Pragma("unroll")                                                        \
      for (int n = 0; n < 2; ++n)                                              \
        _Pragma("unroll")                                                      \
        for (int ks = 0; ks < 2; ++ks)                                         \
          acc[4 + m][n] = __builtin_amdgcn_mfma_f32_16x16x32_bf16(             \
              ah[m][ks], BLc[n][ks], acc[4 + m][n], 0, 0, 0);                  \
  }

#pragma unroll 1
  for (int tp = 0; tp < 8; ++tp) {
    TILE_BODY(2 * tp,     0, blA, blB);
    TILE_BODY(2 * tp + 1, 1, blB, blA);
  }
#undef TILE_BODY

  // epilogue: tanh -> bf16 -> LDS transpose (stride 264 u16, 16B rows, 2 halves)
#pragma unroll 1
  for (int hp = 0; hp < 2; ++hp) {
    if (wm == hp) {
#pragma unroll
      for (int m = 0; m < 8; ++m)
#pragma unroll
        for (int n = 0; n < 4; ++n)
#pragma unroll
          for (int r = 0; r < 4; ++r) {
            const int lr = m * 16 + quad * 4 + r;       // row within half
            const float v = acc[m][n][r];
            const float e = __expf(2.0f * v);           // tanh, saturating, no NaN
            S[lr * 264 + wn * 64 + n * 16 + rl] = f2b(1.0f - 2.0f / (e + 1.0f));
          }
    }
    asm volatile("s_waitcnt lgkmcnt(0)" ::: "memory");  // drain ds_writes pre-barrier
    __builtin_amdgcn_s_barrier();
#pragma unroll
    for (int p = 0; p < 8; ++p) {
      const int idx = p * 512 + tid;    // 0..4095
      const int c = idx & 31, rr = idx >> 5;
      *(short8*)&Tb[(size_t)(row0 + hp * 128 + rr) * 4096 + col0 + c * 8] =
          *(const short8*)&S[rr * 264 + c * 8];
    }
    __builtin_amdgcn_s_barrier();
  }
}

// ---------------------------------------------------------------------------
// K2: Ob[b][k*256+y] = sum_n Tb[b][k*512+n] * Wout[y][n]   (8 batched GEMMs)
// bf16 in / bf16 out (plane in ws). Same structure + transpose epilogue.
// ---------------------------------------------------------------------------
__global__ __launch_bounds__(256) void k2_gemm_out(
    const u16* __restrict__ Tb, const u16* __restrict__ Wout,
    u16* __restrict__ Ob) {
  __shared__ u16 S[128 * 136];
  u16* As = S;
  u16* Bs = S + 128 * 64;
  const int tid  = threadIdx.x;
  const int lane = tid & 63;
  const int w    = tid >> 6;
  const int wm   = w >> 1, wn = w & 1;
  const int row0 = blockIdx.x * 128;
  const int y0   = blockIdx.y * 128;
  const int kk   = blockIdx.z;
  const int sr   = tid >> 3;
  const int sc   = ((tid & 7) ^ ((tid >> 3) & 7)) * 8;
  const int ldsw = (w * 8) * 64;

  f32x4 acc[4][4] = {};

  for (int kt = 0; kt < 8; ++kt) {
    const int kb = kt * 64;
#pragma unroll
    for (int ro = 0; ro < 4; ++ro) {
      gload16(Tb + (size_t)(row0 + ro * 32 + sr) * 4096 + kk * 512 + kb + sc,
              &As[ro * 32 * 64 + ldsw]);
      gload16(Wout + (size_t)(y0 + ro * 32 + sr) * 512 + kb + sc,
              &Bs[ro * 32 * 64 + ldsw]);
    }
    __syncthreads();
    const int l7 = lane & 7, quad = lane >> 4, rl = lane & 15;
#pragma unroll
    for (int ks = 0; ks < 2; ++ks) {
      short8 af[4], bf[4];
      const int cs = ((ks * 4 + quad) ^ l7) * 8;
#pragma unroll
      for (int i = 0; i < 4; ++i)
        af[i] = *(const short8*)&As[(wm * 64 + i * 16 + rl) * 64 + cs];
#pragma unroll
      for (int j = 0; j < 4; ++j)
        bf[j] = *(const short8*)&Bs[(wn * 64 + j * 16 + rl) * 64 + cs];
#pragma unroll
      for (int i = 0; i < 4; ++i)
#pragma unroll
        for (int j = 0; j < 4; ++j)
          acc[i][j] = __builtin_amdgcn_mfma_f32_16x16x32_bf16(af[i], bf[j], acc[i][j], 0, 0, 0);
    }
    __syncthreads();
  }

  const int quad = lane >> 4, cl = lane & 15;
#pragma unroll
  for (int i = 0; i < 4; ++i)
#pragma unroll
    for (int j = 0; j < 4; ++j)
#pragma unroll
      for (int r = 0; r < 4; ++r) {
        const int row = wm * 64 + i * 16 + quad * 4 + r;
        const int col = wn * 64 + j * 16 + cl;
        S[row * 136 + col] = f2b(acc[i][j][r]);
      }
  __syncthreads();
#pragma unroll
  for (int it = 0; it < 8; ++it) {
    const int idx = it * 256 + tid;
    const int c = idx & 15;
    const int r = idx >> 4;
    *(short8*)&Ob[(size_t)(row0 + r) * 2048 + kk * 256 + y0 + c * 8] =
        *(const short8*)&S[r * 136 + c * 8];
  }
}

// ---------------------------------------------------------------------------
// K3: epilogue. Block b: reads Tb row + Ob row (bf16, ws), writes f32
// interleaved h_k / out_k (coalesced float4) + h_mix + out.
// ---------------------------------------------------------------------------
__global__ __launch_bounds__(512) void k3_epi(const float* __restrict__ pi,
                                              const u16* __restrict__ Tb,
                                              const u16* __restrict__ Ob,
                                              float* __restrict__ dout) {
  const int b   = blockIdx.x;
  const int tid = threadIdx.x;

  float pif[8];
#pragma unroll
  for (int k = 0; k < 8; ++k) pif[k] = pi[b * 8 + k];

  float tv[8]; float hm = 0.0f;
#pragma unroll
  for (int k = 0; k < 8; ++k) {
    const float v = b2f(Tb[(size_t)b * 4096 + k * 512 + tid]);
    tv[k] = v; hm += pif[k] * v;
  }
  float4* tw = (float4*)&dout[OFF_HK + (size_t)b * 4096 + tid * 8];
  tw[0] = make_float4(tv[0], tv[1], tv[2], tv[3]);
  tw[1] = make_float4(tv[4], tv[5], tv[6], tv[7]);
  dout[OFF_HMIX + (size_t)b * 512 + tid] = hm;

  if (tid < 256) {
    float ov[8]; float om = 0.0f;
#pragma unroll
    for (int k = 0; k < 8; ++k) {
      const float v = b2f(Ob[(size_t)b * 2048 + k * 256 + tid]);
      ov[k] = v; om += pif[k] * v;
    }
    float4* ow = (float4*)&dout[OFF_OK + (size_t)b * 2048 + tid * 8];
    ow[0] = make_float4(ov[0], ov[1], ov[2], ov[3]);
    ow[1] = make_float4(ov[4], ov[5], ov[6], ov[7]);
    dout[OFF_OUT + (size_t)b * 256 + tid] = om;
  }
}

extern "C" void kernel_launch(void* const* d_in, const int* in_sizes, int n_in,
                              void* d_out, int out_size, void* d_ws, size_t ws_size,
                              hipStream_t stream) {
  const float* x    = (const float*)d_in[0];
  const float* h    = (const float*)d_in[1];
  const float* pi   = (const float*)d_in[2];
  const float* Wih  = (const float*)d_in[3];
  const float* Whh  = (const float*)d_in[4];
  const float* Wout = (const float*)d_in[5];
  float* out = (float*)d_out;
  u16* ws  = (u16*)d_ws;

  k0_cvt<<<dim3(8320), 256, 0, stream>>>(x, h, Wih, Whh, Wout, ws);
  k1_gemm_tanh<<<dim3(256), 512, 0, stream>>>(
      ws + WS_XB, ws + WS_HB, ws + WS_WIH, ws + WS_WHH, ws + WS_T);
  k2_gemm_out<<<dim3(32, 2, 8), 256, 0, stream>>>(ws + WS_T, ws + WS_WOUT, ws + WS_OB);
  k3_epi<<<dim3(BATCH), 512, 0, stream>>>(pi, ws + WS_T, ws + WS_OB, out);
}